// Round 11
// baseline (191.130 us; speedup 1.0000x reference)
//
#include <hip/hip_runtime.h>
#include <hip/hip_bf16.h>

#define B_   4
#define S_   4096
#define D_   1024
#define M_   (B_ * S_)   // 16384
#define K_   1024
#define BK   64
#define NT   (K_ / BK)   // 16

typedef __attribute__((ext_vector_type(4))) float f32x4;
typedef __attribute__((ext_vector_type(8))) short bf16x8;
typedef unsigned short ushort_t;
typedef unsigned int uint_t;

#define SCHEDB __builtin_amdgcn_sched_barrier(0)
#define MFMA16(a, b, c) __builtin_amdgcn_mfma_f32_16x16x32_bf16(a, b, c, 0, 0, 0)

__device__ inline ushort_t f2bf(float f) {
    union { float f; unsigned u; } v; v.f = f;
    unsigned r = v.u + 0x7fffu + ((v.u >> 16) & 1u);
    return (ushort_t)(r >> 16);
}
__device__ inline float bf2f(ushort_t s) {
    union { unsigned u; float f; } v; v.u = ((unsigned)s) << 16; return v.f;
}

// ---------------- convert x (fp32) -> bf16, 8 elems/thread ----------------
__global__ void convert_x_kernel(const float4* __restrict__ x, ushort_t* __restrict__ xb) {
    int i = blockIdx.x * 256 + threadIdx.x;
    float4 a = x[2 * i], b = x[2 * i + 1];
    union { ushort_t s[8]; uint4 v; } u;
    u.s[0] = f2bf(a.x); u.s[1] = f2bf(a.y); u.s[2] = f2bf(a.z); u.s[3] = f2bf(a.w);
    u.s[4] = f2bf(b.x); u.s[5] = f2bf(b.y); u.s[6] = f2bf(b.z); u.s[7] = f2bf(b.w);
    ((uint4*)xb)[i] = u.v;
}

// ---- W_in fp32 [1024][2048] -> WinT bf16 [2048][1024], gate/hidden interleaved by 16 cols ----
__global__ void transpose_win_kernel(const float* __restrict__ W, ushort_t* __restrict__ WT) {
    __shared__ float tile[32][33];
    int tx = threadIdx.x, ty = threadIdx.y;
    int n0 = blockIdx.x * 32, k0 = blockIdx.y * 32;
    int ci = (n0 >> 1) + (tx & 15) + ((tx & 16) ? 1024 : 0);
    tile[ty][tx] = W[(long)(k0 + ty) * 2048 + ci];
    __syncthreads();
    WT[(long)(n0 + ty) * 1024 + k0 + tx] = f2bf(tile[tx][ty]);
}

// ---- W_out fp32 [1024][1024] -> WoT bf16 [1024][1024] ----
__global__ void transpose_wo_kernel(const float* __restrict__ W, ushort_t* __restrict__ WT) {
    __shared__ float tile[32][33];
    int tx = threadIdx.x, ty = threadIdx.y;
    int n0 = blockIdx.x * 32, k0 = blockIdx.y * 32;
    tile[ty][tx] = W[(long)(k0 + ty) * 1024 + n0 + tx];
    __syncthreads();
    WT[(long)(n0 + ty) * 1024 + k0 + tx] = f2bf(tile[tx][ty]);
}

__device__ inline void gld16(const char* g, char* l) {
    __builtin_amdgcn_global_load_lds((const __attribute__((address_space(1))) void*)g,
                                     (__attribute__((address_space(3))) void*)l, 16, 0, 0);
}

// ---------------- 256x256 GEMM, 4 waves (128x128 per wave), BK=64, dbuf, 1 barrier/tile ----------------
// LDS buffer (64KB): A [256 rows][128B] at +0, B [256 rows][128B] at +32768.
// Swizzle: LDS slot s (16B) of row r holds global k-slot s ^ (r&7); staged via pre-swizzled source.
template<int NBN, int GATE>
__global__ __launch_bounds__(256, 1) void gemmw_kernel(
    const ushort_t* __restrict__ A, const ushort_t* __restrict__ Bm,
    const float* __restrict__ bias, void* __restrict__ outp)
{
    extern __shared__ char smem[];
    const int tid = threadIdx.x;
    const int l = tid & 63, w = tid >> 6;       // 4 waves
    const int wm = w >> 1, wn = w & 1;          // 2x2 -> 128x128 per wave
    const int lrow = l & 15, kgrp = l >> 4;

    const int nwg = gridDim.x, cpx = nwg >> 3, bid = blockIdx.x;
    const int wg = (bid & 7) * cpx + (bid >> 3);
    const long m0 = (long)(wg / NBN) * 256;
    const long n0 = (long)(wg % NBN) * 256;

    const char* gA = (const char*)A + m0 * 2048;
    const char* gB = (const char*)Bm + n0 * 2048;

    // staging: wave w stages rows [w*64, w*64+64) of A and of B (8 gld16 each)
    const int lsw = (((l & 7) ^ (l >> 3)) << 4);
    const int srow = w * 64 + (l >> 3);          // + j*8
    // fragment ds_read offsets
    const int arow = (wm * 128 + lrow) * 128;
    const int brow = 32768 + (wn * 128 + lrow) * 128;
    const int sw0 = ((kgrp ^ (l & 7)) << 4);         // k-half 0
    const int sw1 = (((4 + kgrp) ^ (l & 7)) << 4);   // k-half 1

    f32x4 acc[8][8];
#pragma unroll
    for (int i = 0; i < 8; ++i)
#pragma unroll
        for (int j = 0; j < 8; ++j) acc[i][j] = f32x4{0.f, 0.f, 0.f, 0.f};

#define STAGEW(t, buf)                                                          \
    do {                                                                        \
        _Pragma("unroll")                                                       \
        for (int j = 0; j < 8; ++j)                                             \
            gld16(gA + (t) * 128 + (srow + j * 8) * 2048 + lsw,                 \
                  (buf) + w * 8192 + j * 1024);                                 \
        _Pragma("unroll")                                                       \
        for (int j = 0; j < 8; ++j)                                             \
            gld16(gB + (t) * 128 + (srow + j * 8) * 2048 + lsw,                 \
                  (buf) + 32768 + w * 8192 + j * 1024);                         \
    } while (0)

    // prologue: stage tiles 0,1; wait tile 0 landed (16 newer in flight); prime k0(0)
    STAGEW(0, smem);
    STAGEW(1, smem + 65536);
    asm volatile("s_waitcnt vmcnt(16)" ::: "memory");
    __builtin_amdgcn_s_barrier();

    bf16x8 a0[8], b0[8], a1[8], b1[8];
#pragma unroll
    for (int fm = 0; fm < 8; ++fm) a0[fm] = *(const bf16x8*)(smem + arow + fm * 2048 + sw0);
#pragma unroll
    for (int fn = 0; fn < 8; ++fn) b0[fn] = *(const bf16x8*)(smem + brow + fn * 2048 + sw0);
    SCHEDB;

    for (int t = 0; t < NT; ++t) {
        char* cur = smem + ((t & 1) << 16);
        char* nxt = smem + (((t + 1) & 1) << 16);

        // 1. issue k1(t) reads (16) -> drain under MFMA k0
#pragma unroll
        for (int fm = 0; fm < 8; ++fm) a1[fm] = *(const bf16x8*)(cur + arow + fm * 2048 + sw1);
#pragma unroll
        for (int fn = 0; fn < 8; ++fn) b1[fn] = *(const bf16x8*)(cur + brow + fn * 2048 + sw1);

        // 2. k0(t) complete (lgkm 4-bit: 15 ~= "16 newest outstanding")
        asm volatile("s_waitcnt lgkmcnt(15)" ::: "memory");
        SCHEDB;

        // 3. MFMA k0: 64 independent accumulates
        __builtin_amdgcn_s_setprio(1);
#pragma unroll
        for (int fm = 0; fm < 8; ++fm)
#pragma unroll
            for (int fn = 0; fn < 8; ++fn)
                acc[fm][fn] = MFMA16(a0[fm], b0[fn], acc[fm][fn]);
        __builtin_amdgcn_s_setprio(0);
        SCHEDB;

        // 4. my cur-reads done + my t+1 stage landed; sync all waves
        asm volatile("s_waitcnt lgkmcnt(0)" ::: "memory");
        asm volatile("s_waitcnt vmcnt(0)" ::: "memory");
        if (t < NT - 1) __builtin_amdgcn_s_barrier();
        SCHEDB;

        // 5. stage t+2 into cur (all waves past their cur reads)
        if (t + 2 < NT) STAGEW(t + 2, cur);

        // 6. issue k0(t+1) reads from nxt -> drain under MFMA k1
        if (t + 1 < NT) {
#pragma unroll
            for (int fm = 0; fm < 8; ++fm) a0[fm] = *(const bf16x8*)(nxt + arow + fm * 2048 + sw0);
#pragma unroll
            for (int fn = 0; fn < 8; ++fn) b0[fn] = *(const bf16x8*)(nxt + brow + fn * 2048 + sw0);
        }
        SCHEDB;

        // 7. MFMA k1
        __builtin_amdgcn_s_setprio(1);
#pragma unroll
        for (int fm = 0; fm < 8; ++fm)
#pragma unroll
            for (int fn = 0; fn < 8; ++fn)
                acc[fm][fn] = MFMA16(a1[fm], b1[fn], acc[fm][fn]);
        __builtin_amdgcn_s_setprio(0);
        SCHEDB;
    }
#undef STAGEW

    // ---------------- epilogue ----------------
    const long row0 = m0 + wm * 128 + kgrp * 4;
    if (GATE) {
        ushort_t* g = (ushort_t*)outp;
#pragma unroll
        for (int fm = 0; fm < 8; ++fm) {
#pragma unroll
            for (int fp = 0; fp < 4; ++fp) {
                int c = (int)(n0 >> 1) + wn * 64 + fp * 16 + lrow;
                float bg = bias[c], bh = bias[1024 + c];
#pragma unroll
                for (int r = 0; r < 4; ++r) {
                    long rr = row0 + fm * 16 + r;
                    float gate = acc[fm][fp * 2][r] + bg;
                    float hid  = acc[fm][fp * 2 + 1][r] + bh;
                    float sg = 1.0f / (1.0f + expf(-gate));
                    float sh = 1.0f / (1.0f + expf(-hid));
                    g[rr * 1024 + c] = f2bf(sg * hid * sh);
                }
            }
        }
    } else {
        float* o = (float*)outp;
#pragma unroll
        for (int fm = 0; fm < 8; ++fm)
#pragma unroll
            for (int fn = 0; fn < 8; ++fn) {
                int c = (int)n0 + wn * 128 + fn * 16 + lrow;
                float bo = bias[c];
#pragma unroll
                for (int r = 0; r < 4; ++r) {
                    long rr = row0 + fm * 16 + r;
                    o[rr * 1024 + c] = acc[fm][fn][r] + bo;
                }
            }
    }
}

// ---------------- EMA scan: 256 blocks, CS=128, HALO=96, 2 channels/thread ----------------
__global__ void scan_kernel(const ushort_t* __restrict__ g, ushort_t* __restrict__ h) {
    int idx = blockIdx.x * 256 + threadIdx.x;
    int b = idx >> 9, d = (idx & 511) * 2;
    int chunk = blockIdx.y;
    const ushort_t* gb = g + (long)b * S_ * 1024 + d;
    ushort_t* hb = h + (long)b * S_ * 1024 + d;
    float h0 = 0.f, h1 = 0.f;
    int t0 = chunk * 128;
    int tw = t0 - 96; if (tw < 0) tw = 0;
#pragma unroll 4
    for (int t = tw; t < t0; ++t) {
        uint_t v = *(const uint_t*)(gb + (long)t * 1024);
        h0 = 0.9f * h0 + 0.1f * bf2f((ushort_t)(v & 0xffffu));
        h1 = 0.9f * h1 + 0.1f * bf2f((ushort_t)(v >> 16));
    }
#pragma unroll 4
    for (int t = t0; t < t0 + 128; ++t) {
        uint_t v = *(const uint_t*)(gb + (long)t * 1024);
        h0 = 0.9f * h0 + 0.1f * bf2f((ushort_t)(v & 0xffffu));
        h1 = 0.9f * h1 + 0.1f * bf2f((ushort_t)(v >> 16));
        *(uint_t*)(hb + (long)t * 1024) = (((uint_t)f2bf(h1)) << 16) | (uint_t)f2bf(h0);
    }
}

extern "C" void kernel_launch(void* const* d_in, const int* in_sizes, int n_in,
                              void* d_out, int out_size, void* d_ws, size_t ws_size,
                              hipStream_t stream) {
    const float* x     = (const float*)d_in[0];
    const float* W_in  = (const float*)d_in[1];
    const float* b_in  = (const float*)d_in[2];
    const float* W_out = (const float*)d_in[3];
    const float* b_out = (const float*)d_in[4];
    float* outp = (float*)d_out;

    char* ws = (char*)d_ws;
    ushort_t* xb   = (ushort_t*)ws;                        // 32 MB: x bf16, later reused for h bf16
    ushort_t* winT = (ushort_t*)(ws + 33554432);           // 4 MB
    ushort_t* woT  = (ushort_t*)(ws + 33554432 + 4194304); // 2 MB
    ushort_t* gbuf = (ushort_t*)(ws + 33554432 + 6291456); // 32 MB

    hipFuncSetAttribute((const void*)&gemmw_kernel<8, 1>, hipFuncAttributeMaxDynamicSharedMemorySize, 131072);
    hipFuncSetAttribute((const void*)&gemmw_kernel<4, 0>, hipFuncAttributeMaxDynamicSharedMemorySize, 131072);

    convert_x_kernel<<<8192, 256, 0, stream>>>((const float4*)x, xb);
    transpose_win_kernel<<<dim3(64, 32), dim3(32, 32), 0, stream>>>(W_in, winT);
    transpose_wo_kernel<<<dim3(32, 32), dim3(32, 32), 0, stream>>>(W_out, woT);
    gemmw_kernel<8, 1><<<512, 256, 131072, stream>>>(xb, winT, b_in, (void*)gbuf);
    scan_kernel<<<dim3(8, 32), 256, 0, stream>>>(gbuf, xb);
    gemmw_kernel<4, 0><<<256, 256, 131072, stream>>>(xb, woT, b_out, (void*)outp);
}